// Round 1
// baseline (12078.806 us; speedup 1.0000x reference)
//
#include <hip/hip_runtime.h>
#include <math.h>

// ---------- helpers ----------

__device__ __forceinline__ unsigned enc_f(float f) {
    unsigned u = __float_as_uint(f);
    return (u & 0x80000000u) ? ~u : (u | 0x80000000u);
}
__device__ __forceinline__ float dec_f(unsigned u) {
    return (u & 0x80000000u) ? __uint_as_float(u ^ 0x80000000u) : __uint_as_float(~u);
}

// ---------- compose relation-specific weights ----------
// k' = x @ (Wk . blockdiag(att)) * pri/4 ; v' = x @ (Wv . blockdiag(msg))
// WkC[r][i][h*16+e] = pri[r][h]/4 * sum_d Wk[sel][i][h*16+d] * att[r][h][d][e]
__global__ void compose_kernel(const float* __restrict__ Wk, const float* __restrict__ bk,
                               const float* __restrict__ Wv, const float* __restrict__ bv,
                               const float* __restrict__ att, const float* __restrict__ msg,
                               const float* __restrict__ pri,
                               float* __restrict__ WkC, float* __restrict__ bkC,
                               float* __restrict__ WvC, float* __restrict__ bvC) {
    int tid = blockIdx.x * blockDim.x + threadIdx.x;
    if (tid >= 3 * 128 * 128) return;
    int r = tid / 16384;
    int rem = tid & 16383;
    int i = rem >> 7;       // input dim
    int c = rem & 127;      // output dim
    int h = c >> 4, e = c & 15;
    int wsel = (r == 1) ? 1 : 0;
    float p = pri[r * 8 + h] * 0.25f;   // 1/sqrt(16) = 0.25

    const float* wkrow = Wk + wsel * 16384 + i * 128 + h * 16;
    const float* wvrow = Wv + wsel * 16384 + i * 128 + h * 16;
    const float* attc = att + ((r * 8 + h) * 16) * 16 + e;
    const float* msgc = msg + ((r * 8 + h) * 16) * 16 + e;
    float aK = 0.f, aV = 0.f;
#pragma unroll
    for (int d = 0; d < 16; ++d) {
        aK += wkrow[d] * attc[d * 16];
        aV += wvrow[d] * msgc[d * 16];
    }
    WkC[r * 16384 + i * 128 + c] = aK * p;
    WvC[r * 16384 + i * 128 + c] = aV;
    if (i == 0) {
        const float* bkr = bk + wsel * 128 + h * 16;
        const float* bvr = bv + wsel * 128 + h * 16;
        float bK = 0.f, bV = 0.f;
#pragma unroll
        for (int d = 0; d < 16; ++d) {
            bK += bkr[d] * attc[d * 16];
            bV += bvr[d] * msgc[d * 16];
        }
        bkC[r * 128 + c] = bK * p;
        bvC[r * 128 + c] = bV;
    }
}

// ---------- GEMM: Y[n][c] = X[n][:] @ W[:, c] + bias[c], optional gated residual ----------
// 128 rows per block, 256 threads, W staged in LDS, 8x8 micro-tile.
__global__ __launch_bounds__(256) void gemm128_kernel(
    const float* __restrict__ X, const float* __restrict__ W,
    const float* __restrict__ bias, float* __restrict__ Y, int nrows,
    const float* __restrict__ skipv, int skipidx, const float* __restrict__ resid) {
    __shared__ float ws[128 * 128];
    __shared__ float bs[128];
    int tid = threadIdx.x;
    int cg = tid & 15;       // col group: cols cg*8 .. cg*8+7
    int rg = tid >> 4;       // row group: rows rg + 16*i

    // stage W into LDS, coalesced
#pragma unroll
    for (int i = 0; i < 8; ++i) {
        int r = i * 16 + rg;
        int col = cg * 8;
        const float4* s4 = (const float4*)(W + r * 128 + col);
        float4 a = s4[0], b = s4[1];
        *(float4*)&ws[r * 128 + col] = a;
        *(float4*)&ws[r * 128 + col + 4] = b;
    }
    if (tid < 128) bs[tid] = bias[tid];
    __syncthreads();

    int n0 = blockIdx.x * 128;
    int rows_in = nrows - n0;

    float acc[8][8];
    float bj[8];
#pragma unroll
    for (int j = 0; j < 8; ++j) bj[j] = bs[cg * 8 + j];
#pragma unroll
    for (int i = 0; i < 8; ++i)
#pragma unroll
        for (int j = 0; j < 8; ++j) acc[i][j] = bj[j];

    int rowidx[8];
#pragma unroll
    for (int i = 0; i < 8; ++i) {
        int rr = rg + 16 * i;
        rowidx[i] = n0 + (rr < rows_in ? rr : 0);
    }

    for (int k0 = 0; k0 < 128; k0 += 4) {
        float wreg[4][8];
#pragma unroll
        for (int kk = 0; kk < 4; ++kk) {
            const float* wr = &ws[(k0 + kk) * 128 + cg * 8];
            float4 a = *(const float4*)wr;
            float4 b = *(const float4*)(wr + 4);
            wreg[kk][0] = a.x; wreg[kk][1] = a.y; wreg[kk][2] = a.z; wreg[kk][3] = a.w;
            wreg[kk][4] = b.x; wreg[kk][5] = b.y; wreg[kk][6] = b.z; wreg[kk][7] = b.w;
        }
#pragma unroll
        for (int i = 0; i < 8; ++i) {
            float4 xv = *(const float4*)(X + (size_t)rowidx[i] * 128 + k0);
            float xk[4] = {xv.x, xv.y, xv.z, xv.w};
#pragma unroll
            for (int kk = 0; kk < 4; ++kk)
#pragma unroll
                for (int j = 0; j < 8; ++j) acc[i][j] += xk[kk] * wreg[kk][j];
        }
    }

    float alpha = 1.f, beta = 0.f;
    bool has_resid = (resid != nullptr);
    if (has_resid) {
        float s = skipv[skipidx];
        alpha = 1.f / (1.f + __expf(-s));
        beta = 1.f - alpha;
    }
#pragma unroll
    for (int i = 0; i < 8; ++i) {
        int rr = rg + 16 * i;
        if (rr < rows_in) {
            size_t base = (size_t)(n0 + rr) * 128 + cg * 8;
            float o[8];
#pragma unroll
            for (int j = 0; j < 8; ++j) o[j] = acc[i][j];
            if (has_resid) {
#pragma unroll
                for (int j = 0; j < 8; ++j) o[j] = alpha * acc[i][j] + beta * resid[base + j];
            }
            *(float4*)&Y[base] = make_float4(o[0], o[1], o[2], o[3]);
            *(float4*)&Y[base + 4] = make_float4(o[4], o[5], o[6], o[7]);
        }
    }
}

// ---------- pass A: per-edge per-head score + segment max ----------
__global__ void edge_score_kernel(const float* __restrict__ q, const float* __restrict__ k,
                                  const int* __restrict__ src, const int* __restrict__ dst,
                                  float* __restrict__ scores, unsigned* __restrict__ smax, int E) {
    int tid = blockIdx.x * 256 + threadIdx.x;
    int e = tid >> 3;
    if (e >= E) return;
    int h = tid & 7;
    int s = src[e], d = dst[e];
    const float4* qp = (const float4*)(q + (size_t)d * 128 + h * 16);
    const float4* kp = (const float4*)(k + (size_t)s * 128 + h * 16);
    float acc = 0.f;
#pragma unroll
    for (int j = 0; j < 4; ++j) {
        float4 a = qp[j], b = kp[j];
        acc += a.x * b.x + a.y * b.y + a.z * b.z + a.w * b.w;
    }
    scores[(size_t)e * 8 + h] = acc;
    atomicMax(smax + (size_t)d * 8 + h, enc_f(acc));
}

// ---------- pass B: exp, denom, unnormalized message aggregation ----------
__global__ void edge_soft_kernel(const float* __restrict__ v, const int* __restrict__ src,
                                 const int* __restrict__ dst, const float* __restrict__ scores,
                                 const unsigned* __restrict__ smax, float* __restrict__ den,
                                 float* __restrict__ t_un, int E) {
    int tid = blockIdx.x * 256 + threadIdx.x;
    int e = tid >> 3;
    if (e >= E) return;
    int h = tid & 7;
    int s = src[e], d = dst[e];
    float m = dec_f(smax[(size_t)d * 8 + h]);
    float ex = __expf(scores[(size_t)e * 8 + h] - m);
    atomicAdd(den + (size_t)d * 8 + h, ex);
    const float4* vp = (const float4*)(v + (size_t)s * 128 + h * 16);
    float* tp = t_un + (size_t)d * 128 + h * 16;
#pragma unroll
    for (int j = 0; j < 4; ++j) {
        float4 vv = vp[j];
        atomicAdd(tp + 4 * j + 0, ex * vv.x);
        atomicAdd(tp + 4 * j + 1, ex * vv.y);
        atomicAdd(tp + 4 * j + 2, ex * vv.z);
        atomicAdd(tp + 4 * j + 3, ex * vv.w);
    }
}

// ---------- pass C: normalize and accumulate into t_a / t_b ----------
__global__ void norm_acc_kernel(const float* __restrict__ t_un, const float* __restrict__ den,
                                float* __restrict__ tgt, float w, int accum, int Ntot) {
    int tid = blockIdx.x * 256 + threadIdx.x;
    if (tid >= Ntot) return;
    int n = tid >> 7;
    int c = tid & 127;
    int h = c >> 4;
    float dn = den[n * 8 + h];
    float val = (dn > 0.f) ? (t_un[tid] / dn) * w : 0.f;
    if (accum) tgt[tid] += val; else tgt[tid] = val;
}

// ---------- launch ----------
extern "C" void kernel_launch(void* const* d_in, const int* in_sizes, int n_in,
                              void* d_out, int out_size, void* d_ws, size_t ws_size,
                              hipStream_t stream) {
    const float* h_a = (const float*)d_in[0];
    const float* h_b = (const float*)d_in[1];
    const int* srcs[3] = {(const int*)d_in[2], (const int*)d_in[4], (const int*)d_in[6]};
    const int* dsts[3] = {(const int*)d_in[3], (const int*)d_in[5], (const int*)d_in[7]};
    const float* Wk = (const float*)d_in[8];
    const float* bk = (const float*)d_in[9];
    const float* Wv = (const float*)d_in[10];
    const float* bv = (const float*)d_in[11];
    const float* Wq = (const float*)d_in[12];
    const float* bq = (const float*)d_in[13];
    const float* Wa = (const float*)d_in[14];
    const float* ba = (const float*)d_in[15];
    const float* att = (const float*)d_in[16];
    const float* msg = (const float*)d_in[17];
    const float* pri = (const float*)d_in[18];
    const float* skip = (const float*)d_in[19];

    const int N = in_sizes[0] / 128;
    const int E = in_sizes[2];

    float* F = (float*)d_ws;
    float* WkC = F;  F += 3 * 16384;
    float* WvC = F;  F += 3 * 16384;
    float* bkC = F;  F += 3 * 128;
    float* bvC = F;  F += 3 * 128;
    float* q_a  = F; F += (size_t)N * 128;
    float* q_b  = F; F += (size_t)N * 128;
    float* kbuf = F; F += (size_t)N * 128;
    float* vbuf = F; F += (size_t)N * 128;
    float* t_a  = F; F += (size_t)N * 128;
    float* t_b  = F; F += (size_t)N * 128;
    float* t_un = F; F += (size_t)N * 128;
    float* scores = F; F += (size_t)E * 8;
    float* den = F;  F += (size_t)N * 8;
    unsigned* smax = (unsigned*)F; F += (size_t)N * 8;

    compose_kernel<<<(3 * 16384 + 255) / 256, 256, 0, stream>>>(
        Wk, bk, Wv, bv, att, msg, pri, WkC, bkC, WvC, bvC);

    int gblocks = (N + 127) / 128;
    // Q projections (q of dst type): q_a uses Wq[0], q_b uses Wq[1]
    gemm128_kernel<<<gblocks, 256, 0, stream>>>(h_a, Wq, bq, q_a, N, nullptr, 0, nullptr);
    gemm128_kernel<<<gblocks, 256, 0, stream>>>(h_b, Wq + 16384, bq + 128, q_b, N, nullptr, 0, nullptr);

    const float* xsrc[3] = {h_a, h_b, h_a};
    const float* qdst[3] = {q_b, q_a, q_b};
    float* tgt[3] = {t_b, t_a, t_b};
    const float wrel[3] = {0.5f, 1.0f, 0.5f};
    const int accum[3] = {0, 0, 1};

    int eb = (E * 8 + 255) / 256;
    int nthread_norm = N * 128;
    int nb = (nthread_norm + 255) / 256;

    for (int r = 0; r < 3; ++r) {
        gemm128_kernel<<<gblocks, 256, 0, stream>>>(xsrc[r], WkC + r * 16384, bkC + r * 128,
                                                    kbuf, N, nullptr, 0, nullptr);
        gemm128_kernel<<<gblocks, 256, 0, stream>>>(xsrc[r], WvC + r * 16384, bvC + r * 128,
                                                    vbuf, N, nullptr, 0, nullptr);
        hipMemsetAsync(smax, 0, (size_t)N * 8 * sizeof(unsigned), stream);
        hipMemsetAsync(den, 0, (size_t)N * 8 * sizeof(float), stream);
        hipMemsetAsync(t_un, 0, (size_t)N * 128 * sizeof(float), stream);
        edge_score_kernel<<<eb, 256, 0, stream>>>(qdst[r], kbuf, srcs[r], dsts[r], scores, smax, E);
        edge_soft_kernel<<<eb, 256, 0, stream>>>(vbuf, srcs[r], dsts[r], scores, smax, den, t_un, E);
        norm_acc_kernel<<<nb, 256, 0, stream>>>(t_un, den, tgt[r], wrel[r], accum[r], nthread_norm);
    }

    float* out = (float*)d_out;
    gemm128_kernel<<<gblocks, 256, 0, stream>>>(t_a, Wa, ba, out, N, skip, 0, h_a);
    gemm128_kernel<<<gblocks, 256, 0, stream>>>(t_b, Wa + 16384, ba + 128, out + (size_t)N * 128,
                                                N, skip, 1, h_b);
}

// Round 2
// 1326.121 us; speedup vs baseline: 9.1084x; 9.1084x over previous
//
#include <hip/hip_runtime.h>
#include <math.h>

// ---------- compose relation-specific weights ----------
// k' = x @ (Wk . blockdiag(att)) * pri/4 ; v' = x @ (Wv . blockdiag(msg))
__global__ void compose_kernel(const float* __restrict__ Wk, const float* __restrict__ bk,
                               const float* __restrict__ Wv, const float* __restrict__ bv,
                               const float* __restrict__ att, const float* __restrict__ msg,
                               const float* __restrict__ pri,
                               float* __restrict__ WkC, float* __restrict__ bkC,
                               float* __restrict__ WvC, float* __restrict__ bvC) {
    int tid = blockIdx.x * blockDim.x + threadIdx.x;
    if (tid >= 3 * 128 * 128) return;
    int r = tid / 16384;
    int rem = tid & 16383;
    int i = rem >> 7;       // input dim
    int c = rem & 127;      // output dim
    int h = c >> 4, e = c & 15;
    int wsel = (r == 1) ? 1 : 0;
    float p = pri[r * 8 + h] * 0.25f;   // 1/sqrt(16) = 0.25

    const float* wkrow = Wk + wsel * 16384 + i * 128 + h * 16;
    const float* wvrow = Wv + wsel * 16384 + i * 128 + h * 16;
    const float* attc = att + ((r * 8 + h) * 16) * 16 + e;
    const float* msgc = msg + ((r * 8 + h) * 16) * 16 + e;
    float aK = 0.f, aV = 0.f;
#pragma unroll
    for (int d = 0; d < 16; ++d) {
        aK += wkrow[d] * attc[d * 16];
        aV += wvrow[d] * msgc[d * 16];
    }
    WkC[r * 16384 + i * 128 + c] = aK * p;
    WvC[r * 16384 + i * 128 + c] = aV;
    if (i == 0) {
        const float* bkr = bk + wsel * 128 + h * 16;
        const float* bvr = bv + wsel * 128 + h * 16;
        float bK = 0.f, bV = 0.f;
#pragma unroll
        for (int d = 0; d < 16; ++d) {
            bK += bkr[d] * attc[d * 16];
            bV += bvr[d] * msgc[d * 16];
        }
        bkC[r * 128 + c] = bK * p;
        bvC[r * 128 + c] = bV;
    }
}

// ---------- GEMM: Y[n][c] = X[n][:] @ W[:, c] + bias[c], optional gated residual ----------
__global__ __launch_bounds__(256) void gemm128_kernel(
    const float* __restrict__ X, const float* __restrict__ W,
    const float* __restrict__ bias, float* __restrict__ Y, int nrows,
    const float* __restrict__ skipv, int skipidx, const float* __restrict__ resid) {
    __shared__ float ws[128 * 128];
    __shared__ float bs[128];
    int tid = threadIdx.x;
    int cg = tid & 15;       // col group: cols cg*8 .. cg*8+7
    int rg = tid >> 4;       // row group: rows rg + 16*i

#pragma unroll
    for (int i = 0; i < 8; ++i) {
        int r = i * 16 + rg;
        int col = cg * 8;
        const float4* s4 = (const float4*)(W + r * 128 + col);
        float4 a = s4[0], b = s4[1];
        *(float4*)&ws[r * 128 + col] = a;
        *(float4*)&ws[r * 128 + col + 4] = b;
    }
    if (tid < 128) bs[tid] = bias[tid];
    __syncthreads();

    int n0 = blockIdx.x * 128;
    int rows_in = nrows - n0;

    float acc[8][8];
    float bj[8];
#pragma unroll
    for (int j = 0; j < 8; ++j) bj[j] = bs[cg * 8 + j];
#pragma unroll
    for (int i = 0; i < 8; ++i)
#pragma unroll
        for (int j = 0; j < 8; ++j) acc[i][j] = bj[j];

    int rowidx[8];
#pragma unroll
    for (int i = 0; i < 8; ++i) {
        int rr = rg + 16 * i;
        rowidx[i] = n0 + (rr < rows_in ? rr : 0);
    }

    for (int k0 = 0; k0 < 128; k0 += 4) {
        float wreg[4][8];
#pragma unroll
        for (int kk = 0; kk < 4; ++kk) {
            const float* wr = &ws[(k0 + kk) * 128 + cg * 8];
            float4 a = *(const float4*)wr;
            float4 b = *(const float4*)(wr + 4);
            wreg[kk][0] = a.x; wreg[kk][1] = a.y; wreg[kk][2] = a.z; wreg[kk][3] = a.w;
            wreg[kk][4] = b.x; wreg[kk][5] = b.y; wreg[kk][6] = b.z; wreg[kk][7] = b.w;
        }
#pragma unroll
        for (int i = 0; i < 8; ++i) {
            float4 xv = *(const float4*)(X + (size_t)rowidx[i] * 128 + k0);
            float xk[4] = {xv.x, xv.y, xv.z, xv.w};
#pragma unroll
            for (int kk = 0; kk < 4; ++kk)
#pragma unroll
                for (int j = 0; j < 8; ++j) acc[i][j] += xk[kk] * wreg[kk][j];
        }
    }

    float alpha = 1.f, beta = 0.f;
    bool has_resid = (resid != nullptr);
    if (has_resid) {
        float s = skipv[skipidx];
        alpha = 1.f / (1.f + __expf(-s));
        beta = 1.f - alpha;
    }
#pragma unroll
    for (int i = 0; i < 8; ++i) {
        int rr = rg + 16 * i;
        if (rr < rows_in) {
            size_t base = (size_t)(n0 + rr) * 128 + cg * 8;
            float o[8];
#pragma unroll
            for (int j = 0; j < 8; ++j) o[j] = acc[i][j];
            if (has_resid) {
#pragma unroll
                for (int j = 0; j < 8; ++j) o[j] = alpha * acc[i][j] + beta * resid[base + j];
            }
            *(float4*)&Y[base] = make_float4(o[0], o[1], o[2], o[3]);
            *(float4*)&Y[base + 4] = make_float4(o[4], o[5], o[6], o[7]);
        }
    }
}

// ---------- CSR build ----------
__global__ void count_kernel(const int* __restrict__ dst, int* __restrict__ cnt, int E) {
    int e = blockIdx.x * 256 + threadIdx.x;
    if (e < E) atomicAdd(&cnt[dst[e]], 1);
}

#define SCAN_B 256
__global__ void scan1_kernel(const int* __restrict__ cnt, int* __restrict__ offs,
                             int* __restrict__ bsum, int n) {
    __shared__ int sh[SCAN_B];
    int i = blockIdx.x * SCAN_B + threadIdx.x;
    int v = (i < n) ? cnt[i] : 0;
    sh[threadIdx.x] = v;
    __syncthreads();
    for (int off = 1; off < SCAN_B; off <<= 1) {
        int t = (threadIdx.x >= off) ? sh[threadIdx.x - off] : 0;
        __syncthreads();
        sh[threadIdx.x] += t;
        __syncthreads();
    }
    if (i < n) offs[i] = sh[threadIdx.x] - v;   // exclusive
    if (threadIdx.x == SCAN_B - 1) bsum[blockIdx.x] = sh[threadIdx.x];
}

__global__ void scan2_kernel(int* __restrict__ bsum, int nb) {
    __shared__ int sh[512];
    int v = (threadIdx.x < nb) ? bsum[threadIdx.x] : 0;
    sh[threadIdx.x] = v;
    __syncthreads();
    for (int off = 1; off < 512; off <<= 1) {
        int t = (threadIdx.x >= off) ? sh[threadIdx.x - off] : 0;
        __syncthreads();
        sh[threadIdx.x] += t;
        __syncthreads();
    }
    if (threadIdx.x < nb) bsum[threadIdx.x] = sh[threadIdx.x] - v;  // exclusive
}

__global__ void scan3_kernel(int* __restrict__ offs, const int* __restrict__ bsum,
                             int* __restrict__ fill, int n) {
    int i = blockIdx.x * SCAN_B + threadIdx.x;
    if (i < n) {
        int o = offs[i] + bsum[blockIdx.x];
        offs[i] = o;
        fill[i] = o;
    }
}

__global__ void scatter_kernel(const int* __restrict__ src, const int* __restrict__ dst,
                               int* __restrict__ fill, int* __restrict__ ss, int E) {
    int e = blockIdx.x * 256 + threadIdx.x;
    if (e < E) {
        int p = atomicAdd(&fill[dst[e]], 1);
        ss[p] = src[e];
    }
}

// ---------- fused online-softmax aggregation: one thread per (dst, head) ----------
__global__ __launch_bounds__(256) void agg_kernel(
    const float* __restrict__ q, const float* __restrict__ k, const float* __restrict__ v,
    const int* __restrict__ offs, const int* __restrict__ cnt, const int* __restrict__ ss,
    float* __restrict__ tgt, float w, int accum, int N8) {
    int t = blockIdx.x * 256 + threadIdx.x;
    if (t >= N8) return;
    int n = t >> 3, h = t & 7;
    const float4* qp = (const float4*)(q + (size_t)n * 128 + h * 16);
    float4 q0 = qp[0], q1 = qp[1], q2 = qp[2], q3 = qp[3];
    int start = offs[n], deg = cnt[n];
    float m = -3.0e38f, den = 0.f;
    float4 a0 = make_float4(0, 0, 0, 0), a1 = a0, a2 = a0, a3 = a0;
    for (int i = 0; i < deg; ++i) {
        int s = ss[start + i];
        const float4* kp = (const float4*)(k + (size_t)s * 128 + h * 16);
        float4 k0 = kp[0], k1 = kp[1], k2 = kp[2], k3 = kp[3];
        float sc = q0.x * k0.x + q0.y * k0.y + q0.z * k0.z + q0.w * k0.w
                 + q1.x * k1.x + q1.y * k1.y + q1.z * k1.z + q1.w * k1.w
                 + q2.x * k2.x + q2.y * k2.y + q2.z * k2.z + q2.w * k2.w
                 + q3.x * k3.x + q3.y * k3.y + q3.z * k3.z + q3.w * k3.w;
        float mn = fmaxf(m, sc);
        float scale = __expf(m - mn);
        float ex = __expf(sc - mn);
        den = den * scale + ex;
        const float4* vp = (const float4*)(v + (size_t)s * 128 + h * 16);
        float4 v0 = vp[0], v1 = vp[1], v2 = vp[2], v3 = vp[3];
        a0.x = a0.x * scale + ex * v0.x; a0.y = a0.y * scale + ex * v0.y;
        a0.z = a0.z * scale + ex * v0.z; a0.w = a0.w * scale + ex * v0.w;
        a1.x = a1.x * scale + ex * v1.x; a1.y = a1.y * scale + ex * v1.y;
        a1.z = a1.z * scale + ex * v1.z; a1.w = a1.w * scale + ex * v1.w;
        a2.x = a2.x * scale + ex * v2.x; a2.y = a2.y * scale + ex * v2.y;
        a2.z = a2.z * scale + ex * v2.z; a2.w = a2.w * scale + ex * v2.w;
        a3.x = a3.x * scale + ex * v3.x; a3.y = a3.y * scale + ex * v3.y;
        a3.z = a3.z * scale + ex * v3.z; a3.w = a3.w * scale + ex * v3.w;
        m = mn;
    }
    float inv = (deg > 0) ? (w / den) : 0.f;
    float* tp = tgt + (size_t)n * 128 + h * 16;
    if (accum) {
        float4 o0 = *(float4*)(tp + 0), o1 = *(float4*)(tp + 4);
        float4 o2 = *(float4*)(tp + 8), o3 = *(float4*)(tp + 12);
        o0.x += a0.x * inv; o0.y += a0.y * inv; o0.z += a0.z * inv; o0.w += a0.w * inv;
        o1.x += a1.x * inv; o1.y += a1.y * inv; o1.z += a1.z * inv; o1.w += a1.w * inv;
        o2.x += a2.x * inv; o2.y += a2.y * inv; o2.z += a2.z * inv; o2.w += a2.w * inv;
        o3.x += a3.x * inv; o3.y += a3.y * inv; o3.z += a3.z * inv; o3.w += a3.w * inv;
        *(float4*)(tp + 0) = o0; *(float4*)(tp + 4) = o1;
        *(float4*)(tp + 8) = o2; *(float4*)(tp + 12) = o3;
    } else {
        *(float4*)(tp + 0) = make_float4(a0.x * inv, a0.y * inv, a0.z * inv, a0.w * inv);
        *(float4*)(tp + 4) = make_float4(a1.x * inv, a1.y * inv, a1.z * inv, a1.w * inv);
        *(float4*)(tp + 8) = make_float4(a2.x * inv, a2.y * inv, a2.z * inv, a2.w * inv);
        *(float4*)(tp + 12) = make_float4(a3.x * inv, a3.y * inv, a3.z * inv, a3.w * inv);
    }
}

// ---------- launch ----------
extern "C" void kernel_launch(void* const* d_in, const int* in_sizes, int n_in,
                              void* d_out, int out_size, void* d_ws, size_t ws_size,
                              hipStream_t stream) {
    const float* h_a = (const float*)d_in[0];
    const float* h_b = (const float*)d_in[1];
    const int* srcs[3] = {(const int*)d_in[2], (const int*)d_in[4], (const int*)d_in[6]};
    const int* dsts[3] = {(const int*)d_in[3], (const int*)d_in[5], (const int*)d_in[7]};
    const float* Wk = (const float*)d_in[8];
    const float* bk = (const float*)d_in[9];
    const float* Wv = (const float*)d_in[10];
    const float* bv = (const float*)d_in[11];
    const float* Wq = (const float*)d_in[12];
    const float* bq = (const float*)d_in[13];
    const float* Wa = (const float*)d_in[14];
    const float* ba = (const float*)d_in[15];
    const float* att = (const float*)d_in[16];
    const float* msg = (const float*)d_in[17];
    const float* pri = (const float*)d_in[18];
    const float* skip = (const float*)d_in[19];

    const int N = in_sizes[0] / 128;
    const int E = in_sizes[2];

    float* F = (float*)d_ws;
    float* WkC = F;  F += 3 * 16384;
    float* WvC = F;  F += 3 * 16384;
    float* bkC = F;  F += 3 * 128;
    float* bvC = F;  F += 3 * 128;
    float* q_a  = F; F += (size_t)N * 128;
    float* q_b  = F; F += (size_t)N * 128;
    float* kbuf = F; F += (size_t)N * 128;
    float* vbuf = F; F += (size_t)N * 128;
    float* t_a  = F; F += (size_t)N * 128;
    float* t_b  = F; F += (size_t)N * 128;
    int* cnt  = (int*)F; F += N;
    int* offs = (int*)F; F += N;
    int* fill = (int*)F; F += N;
    int* bsum = (int*)F; F += 512;
    int* ss   = (int*)F; F += E;

    compose_kernel<<<(3 * 16384 + 255) / 256, 256, 0, stream>>>(
        Wk, bk, Wv, bv, att, msg, pri, WkC, bkC, WvC, bvC);

    int gblocks = (N + 127) / 128;
    gemm128_kernel<<<gblocks, 256, 0, stream>>>(h_a, Wq, bq, q_a, N, nullptr, 0, nullptr);
    gemm128_kernel<<<gblocks, 256, 0, stream>>>(h_b, Wq + 16384, bq + 128, q_b, N, nullptr, 0, nullptr);

    const float* xsrc[3] = {h_a, h_b, h_a};
    const float* qdst[3] = {q_b, q_a, q_b};
    float* tgt[3] = {t_b, t_a, t_b};
    const float wrel[3] = {0.5f, 1.0f, 0.5f};
    const int accum[3] = {0, 0, 1};

    int eb = (E + 255) / 256;
    int scanb = (N + SCAN_B - 1) / SCAN_B;
    int aggb = (N * 8 + 255) / 256;

    for (int r = 0; r < 3; ++r) {
        // CSR build for this relation
        hipMemsetAsync(cnt, 0, (size_t)N * sizeof(int), stream);
        count_kernel<<<eb, 256, 0, stream>>>(dsts[r], cnt, E);
        scan1_kernel<<<scanb, SCAN_B, 0, stream>>>(cnt, offs, bsum, N);
        scan2_kernel<<<1, 512, 0, stream>>>(bsum, scanb);
        scan3_kernel<<<scanb, SCAN_B, 0, stream>>>(offs, bsum, fill, N);
        scatter_kernel<<<eb, 256, 0, stream>>>(srcs[r], dsts[r], fill, ss, E);
        // projections
        gemm128_kernel<<<gblocks, 256, 0, stream>>>(xsrc[r], WkC + r * 16384, bkC + r * 128,
                                                    kbuf, N, nullptr, 0, nullptr);
        gemm128_kernel<<<gblocks, 256, 0, stream>>>(xsrc[r], WvC + r * 16384, bvC + r * 128,
                                                    vbuf, N, nullptr, 0, nullptr);
        // fused online-softmax aggregation
        agg_kernel<<<aggb, 256, 0, stream>>>(qdst[r], kbuf, vbuf, offs, cnt, ss,
                                             tgt[r], wrel[r], accum[r], N * 8);
    }

    float* out = (float*)d_out;
    gemm128_kernel<<<gblocks, 256, 0, stream>>>(t_a, Wa, ba, out, N, skip, 0, h_a);
    gemm128_kernel<<<gblocks, 256, 0, stream>>>(t_b, Wa + 16384, ba + 128, out + (size_t)N * 128,
                                                N, skip, 1, h_b);
}

// Round 3
// 764.012 us; speedup vs baseline: 15.8097x; 1.7357x over previous
//
#include <hip/hip_runtime.h>
#include <math.h>

typedef short bf16x8 __attribute__((ext_vector_type(8)));
typedef float f32x4 __attribute__((ext_vector_type(4)));

__device__ __forceinline__ unsigned short cvt_bf16(float f) {
    unsigned u = __float_as_uint(f);
    u += 0x7fffu + ((u >> 16) & 1);        // round-to-nearest-even
    return (unsigned short)(u >> 16);
}
__device__ __forceinline__ float cvt_f32(unsigned short b) {
    return __uint_as_float(((unsigned)b) << 16);
}

// ---------- compose relation weights, store TRANSPOSED bf16 [c][i] ----------
// k' = x @ (Wk . blockdiag(att)) * pri/4 ; v' = x @ (Wv . blockdiag(msg))
__global__ void compose_kernel(const float* __restrict__ Wk, const float* __restrict__ bk,
                               const float* __restrict__ Wv, const float* __restrict__ bv,
                               const float* __restrict__ att, const float* __restrict__ msg,
                               const float* __restrict__ pri,
                               unsigned short* __restrict__ WkT, unsigned short* __restrict__ WvT,
                               float* __restrict__ bkC, float* __restrict__ bvC) {
    int tid = blockIdx.x * blockDim.x + threadIdx.x;
    if (tid >= 3 * 16384) return;
    int r = tid / 16384;
    int rem = tid & 16383;
    int c = rem >> 7;       // output dim (row of W^T)
    int i = rem & 127;      // input dim
    int h = c >> 4, e = c & 15;
    int wsel = (r == 1) ? 1 : 0;
    float p = pri[r * 8 + h] * 0.25f;   // 1/sqrt(16)

    const float* wkrow = Wk + wsel * 16384 + i * 128 + h * 16;
    const float* wvrow = Wv + wsel * 16384 + i * 128 + h * 16;
    const float* attc = att + ((r * 8 + h) * 16) * 16 + e;
    const float* msgc = msg + ((r * 8 + h) * 16) * 16 + e;
    float aK = 0.f, aV = 0.f;
#pragma unroll
    for (int d = 0; d < 16; ++d) {
        aK += wkrow[d] * attc[d * 16];
        aV += wvrow[d] * msgc[d * 16];
    }
    WkT[r * 16384 + c * 128 + i] = cvt_bf16(aK * p);
    WvT[r * 16384 + c * 128 + i] = cvt_bf16(aV);
    if (i == 0) {
        const float* bkr = bk + wsel * 128 + h * 16;
        const float* bvr = bv + wsel * 128 + h * 16;
        float bK = 0.f, bV = 0.f;
#pragma unroll
        for (int d = 0; d < 16; ++d) {
            bK += bkr[d] * attc[d * 16];
            bV += bvr[d] * msgc[d * 16];
        }
        bkC[r * 128 + c] = bK * p;
        bvC[r * 128 + c] = bV;
    }
}

// ---------- transpose+cast a 128x128 f32 matrix to bf16 W^T ----------
__global__ void tcast_kernel(const float* __restrict__ src, unsigned short* __restrict__ dst) {
    int tid = blockIdx.x * 256 + threadIdx.x;   // 16384 threads
    int c = tid >> 7, i = tid & 127;
    dst[tid] = cvt_bf16(src[i * 128 + c]);      // dst[c][i] = src[i][c]
}

// ---------- cast f32 -> bf16 (vectorized) ----------
__global__ void cast_kernel(const float* __restrict__ src, unsigned short* __restrict__ dst, int n4) {
    int t = blockIdx.x * 256 + threadIdx.x;
    if (t >= n4) return;
    float4 f = ((const float4*)src)[t];
    ushort4 o;
    o.x = cvt_bf16(f.x); o.y = cvt_bf16(f.y); o.z = cvt_bf16(f.z); o.w = cvt_bf16(f.w);
    ((ushort4*)dst)[t] = o;
}

// ---------- multi-output MFMA projection: Y_o = bf16(X @ W_o + b_o) ----------
// X bf16 row-major [M][128]; W_o given TRANSPOSED bf16 [128][128] ([n][k]).
// 128 rows/block, 256 threads (4 waves), K=128 in one pass (4 mfma k-steps).
struct OutSpec { const unsigned short* Wt; const float* bias; unsigned short* out; };
struct OutSpecs { OutSpec o[5]; };

#define LPAD 136   // 128 + 8 bf16 pad: row stride 272 B -> bank step 4, 2-way (free)

__global__ __launch_bounds__(256) void mfma_proj_kernel(const unsigned short* __restrict__ X,
                                                        int nrows, OutSpecs specs, int nout) {
    __shared__ unsigned short Xs[128 * LPAD];
    __shared__ unsigned short Ws[128 * LPAD];
    __shared__ float bs[128];
    int tid = threadIdx.x;
    int n0 = blockIdx.x * 128;
    int rows_in = nrows - n0; if (rows_in > 128) rows_in = 128;

    {   // stage X tile (row-clamped for the partial last block)
        int rowb = tid >> 4, seg = tid & 15;
#pragma unroll
        for (int p = 0; p < 8; ++p) {
            int row = p * 16 + rowb;
            int rowg = row < rows_in ? row : rows_in - 1;
            uint4 d = *(const uint4*)(X + ((size_t)(n0 + rowg)) * 128 + seg * 8);
            *(uint4*)&Xs[row * LPAD + seg * 8] = d;
        }
    }

    int wave = tid >> 6, lane = tid & 63;
    int l15 = lane & 15, quad = lane >> 4;

    for (int o = 0; o < nout; ++o) {
        {   // stage W^T
            int rowb = tid >> 4, seg = tid & 15;
            const unsigned short* Wt = specs.o[o].Wt;
#pragma unroll
            for (int p = 0; p < 8; ++p) {
                int row = p * 16 + rowb;
                uint4 d = *(const uint4*)(Wt + (size_t)row * 128 + seg * 8);
                *(uint4*)&Ws[row * LPAD + seg * 8] = d;
            }
            if (tid < 128) bs[tid] = specs.o[o].bias[tid];
        }
        __syncthreads();

        f32x4 acc[2][8];
#pragma unroll
        for (int mi = 0; mi < 2; ++mi)
#pragma unroll
            for (int nt = 0; nt < 8; ++nt) acc[mi][nt] = (f32x4){0.f, 0.f, 0.f, 0.f};

#pragma unroll
        for (int ks = 0; ks < 4; ++ks) {
            bf16x8 afr[2];
            afr[0] = *(const bf16x8*)&Xs[(wave * 32 + l15) * LPAD + ks * 32 + quad * 8];
            afr[1] = *(const bf16x8*)&Xs[(wave * 32 + 16 + l15) * LPAD + ks * 32 + quad * 8];
#pragma unroll
            for (int nt = 0; nt < 8; ++nt) {
                bf16x8 bfr = *(const bf16x8*)&Ws[(nt * 16 + l15) * LPAD + ks * 32 + quad * 8];
                acc[0][nt] = __builtin_amdgcn_mfma_f32_16x16x32_bf16(afr[0], bfr, acc[0][nt], 0, 0, 0);
                acc[1][nt] = __builtin_amdgcn_mfma_f32_16x16x32_bf16(afr[1], bfr, acc[1][nt], 0, 0, 0);
            }
        }

        unsigned short* out = specs.o[o].out;
#pragma unroll
        for (int mi = 0; mi < 2; ++mi) {
            int rowbase = wave * 32 + mi * 16 + quad * 4;
#pragma unroll
            for (int r = 0; r < 4; ++r) {
                int row = rowbase + r;
                if (row < rows_in) {
#pragma unroll
                    for (int nt = 0; nt < 8; ++nt) {
                        int col = nt * 16 + l15;
                        out[(size_t)(n0 + row) * 128 + col] = cvt_bf16(acc[mi][nt][r] + bs[col]);
                    }
                }
            }
        }
        __syncthreads();
    }
}

// ---------- epilogue MFMA: out = alpha*(T@Wa + ba) + (1-alpha)*h, f32 out ----------
__global__ __launch_bounds__(256) void mfma_out_kernel(const unsigned short* __restrict__ T16,
        int nrows, const unsigned short* __restrict__ WaT, const float* __restrict__ bias,
        const float* __restrict__ resid, const float* __restrict__ skipv, int skipidx,
        float* __restrict__ out) {
    __shared__ unsigned short Xs[128 * LPAD];
    __shared__ unsigned short Ws[128 * LPAD];
    __shared__ float bs[128];
    int tid = threadIdx.x;
    int n0 = blockIdx.x * 128;
    int rows_in = nrows - n0; if (rows_in > 128) rows_in = 128;

    {
        int rowb = tid >> 4, seg = tid & 15;
#pragma unroll
        for (int p = 0; p < 8; ++p) {
            int row = p * 16 + rowb;
            int rowg = row < rows_in ? row : rows_in - 1;
            uint4 d = *(const uint4*)(T16 + ((size_t)(n0 + rowg)) * 128 + seg * 8);
            *(uint4*)&Xs[row * LPAD + seg * 8] = d;
            uint4 w = *(const uint4*)(WaT + (size_t)row * 128 + seg * 8);
            *(uint4*)&Ws[row * LPAD + seg * 8] = w;
        }
        if (tid < 128) bs[tid] = bias[tid];
    }
    __syncthreads();

    int wave = tid >> 6, lane = tid & 63;
    int l15 = lane & 15, quad = lane >> 4;

    f32x4 acc[2][8];
#pragma unroll
    for (int mi = 0; mi < 2; ++mi)
#pragma unroll
        for (int nt = 0; nt < 8; ++nt) acc[mi][nt] = (f32x4){0.f, 0.f, 0.f, 0.f};

#pragma unroll
    for (int ks = 0; ks < 4; ++ks) {
        bf16x8 afr[2];
        afr[0] = *(const bf16x8*)&Xs[(wave * 32 + l15) * LPAD + ks * 32 + quad * 8];
        afr[1] = *(const bf16x8*)&Xs[(wave * 32 + 16 + l15) * LPAD + ks * 32 + quad * 8];
#pragma unroll
        for (int nt = 0; nt < 8; ++nt) {
            bf16x8 bfr = *(const bf16x8*)&Ws[(nt * 16 + l15) * LPAD + ks * 32 + quad * 8];
            acc[0][nt] = __builtin_amdgcn_mfma_f32_16x16x32_bf16(afr[0], bfr, acc[0][nt], 0, 0, 0);
            acc[1][nt] = __builtin_amdgcn_mfma_f32_16x16x32_bf16(afr[1], bfr, acc[1][nt], 0, 0, 0);
        }
    }

    float s = skipv[skipidx];
    float alpha = 1.f / (1.f + __expf(-s));
    float beta = 1.f - alpha;
#pragma unroll
    for (int mi = 0; mi < 2; ++mi) {
        int rowbase = wave * 32 + mi * 16 + quad * 4;
#pragma unroll
        for (int r = 0; r < 4; ++r) {
            int row = rowbase + r;
            if (row < rows_in) {
#pragma unroll
                for (int nt = 0; nt < 8; ++nt) {
                    int col = nt * 16 + l15;
                    size_t gi = (size_t)(n0 + row) * 128 + col;
                    out[gi] = alpha * (acc[mi][nt][r] + bs[col]) + beta * resid[gi];
                }
            }
        }
    }
}

// ---------- CSR build ----------
__global__ void count_kernel(const int* __restrict__ dst, int* __restrict__ cnt, int E) {
    int e = blockIdx.x * 256 + threadIdx.x;
    if (e < E) atomicAdd(&cnt[dst[e]], 1);
}

#define SCAN_B 256
__global__ void scan1_kernel(const int* __restrict__ cnt, int* __restrict__ offs,
                             int* __restrict__ bsum, int n) {
    __shared__ int sh[SCAN_B];
    int i = blockIdx.x * SCAN_B + threadIdx.x;
    int v = (i < n) ? cnt[i] : 0;
    sh[threadIdx.x] = v;
    __syncthreads();
    for (int off = 1; off < SCAN_B; off <<= 1) {
        int t = (threadIdx.x >= off) ? sh[threadIdx.x - off] : 0;
        __syncthreads();
        sh[threadIdx.x] += t;
        __syncthreads();
    }
    if (i < n) offs[i] = sh[threadIdx.x] - v;
    if (threadIdx.x == SCAN_B - 1) bsum[blockIdx.x] = sh[threadIdx.x];
}

__global__ void scan2_kernel(int* __restrict__ bsum, int nb) {
    __shared__ int sh[512];
    int v = (threadIdx.x < nb) ? bsum[threadIdx.x] : 0;
    sh[threadIdx.x] = v;
    __syncthreads();
    for (int off = 1; off < 512; off <<= 1) {
        int t = (threadIdx.x >= off) ? sh[threadIdx.x - off] : 0;
        __syncthreads();
        sh[threadIdx.x] += t;
        __syncthreads();
    }
    if (threadIdx.x < nb) bsum[threadIdx.x] = sh[threadIdx.x] - v;
}

__global__ void scan3_kernel(int* __restrict__ offs, const int* __restrict__ bsum,
                             int* __restrict__ fill, int n) {
    int i = blockIdx.x * SCAN_B + threadIdx.x;
    if (i < n) {
        int o = offs[i] + bsum[blockIdx.x];
        offs[i] = o;
        fill[i] = o;
    }
}

__global__ void scatter_kernel(const int* __restrict__ src, const int* __restrict__ dst,
                               int* __restrict__ fill, int* __restrict__ ss, int E) {
    int e = blockIdx.x * 256 + threadIdx.x;
    if (e < E) {
        int p = atomicAdd(&fill[dst[e]], 1);
        ss[p] = src[e];
    }
}

// ---------- wave-per-node online-softmax aggregation ----------
// lane = j*8 + h (j = edge slot 0..7, h = head). All edge gathers issue in parallel;
// states merged across j by shfl_xor(8,16,32). Lanes j==0 write row t[n][h*16..].
__global__ __launch_bounds__(256) void agg_kernel(
    const unsigned short* __restrict__ q, const unsigned short* __restrict__ k,
    const unsigned short* __restrict__ v, const int* __restrict__ offs,
    const int* __restrict__ cnt, const int* __restrict__ ss,
    const float* __restrict__ acc_in, void* __restrict__ outp, int out_bf16,
    float w, int N) {
    int wid = (blockIdx.x * 256 + threadIdx.x) >> 6;   // node
    if (wid >= N) return;
    int lane = threadIdx.x & 63;
    int j = lane >> 3, h = lane & 7;

    const unsigned short* qp = q + (size_t)wid * 128 + h * 16;
    uint4 qa = *(const uint4*)qp, qb = *(const uint4*)(qp + 8);
    float qf[16];
    {
        const unsigned short* qs = (const unsigned short*)&qa;
#pragma unroll
        for (int t = 0; t < 8; ++t) qf[t] = cvt_f32(qs[t]);
        qs = (const unsigned short*)&qb;
#pragma unroll
        for (int t = 0; t < 8; ++t) qf[8 + t] = cvt_f32(qs[t]);
    }

    int start = offs[wid], deg = cnt[wid];
    float m = -3.0e38f, den = 0.f;
    float acc[16];
#pragma unroll
    for (int t = 0; t < 16; ++t) acc[t] = 0.f;

    for (int i = j; i < deg; i += 8) {
        int s = ss[start + i];
        const unsigned short* kp = k + (size_t)s * 128 + h * 16;
        uint4 ka = *(const uint4*)kp, kb = *(const uint4*)(kp + 8);
        const unsigned short* vp = v + (size_t)s * 128 + h * 16;
        uint4 va = *(const uint4*)vp, vb = *(const uint4*)(vp + 8);
        float kf[16], vf[16];
        {
            const unsigned short* p1 = (const unsigned short*)&ka;
#pragma unroll
            for (int t = 0; t < 8; ++t) kf[t] = cvt_f32(p1[t]);
            p1 = (const unsigned short*)&kb;
#pragma unroll
            for (int t = 0; t < 8; ++t) kf[8 + t] = cvt_f32(p1[t]);
            p1 = (const unsigned short*)&va;
#pragma unroll
            for (int t = 0; t < 8; ++t) vf[t] = cvt_f32(p1[t]);
            p1 = (const unsigned short*)&vb;
#pragma unroll
            for (int t = 0; t < 8; ++t) vf[8 + t] = cvt_f32(p1[t]);
        }
        float sc = 0.f;
#pragma unroll
        for (int t = 0; t < 16; ++t) sc += qf[t] * kf[t];
        float mn = fmaxf(m, sc);
        float scale = __expf(m - mn);
        float ex = __expf(sc - mn);
        den = den * scale + ex;
#pragma unroll
        for (int t = 0; t < 16; ++t) acc[t] = acc[t] * scale + ex * vf[t];
        m = mn;
    }

    // butterfly-combine across j (masks 8,16,32); h bits preserved
#pragma unroll
    for (int mask = 8; mask <= 32; mask <<= 1) {
        float mo = __shfl_xor(m, mask);
        float deno = __shfl_xor(den, mask);
        float mn = fmaxf(m, mo);
        float s1 = __expf(m - mn), s2 = __expf(mo - mn);
        den = den * s1 + deno * s2;
#pragma unroll
        for (int t = 0; t < 16; ++t) {
            float ao = __shfl_xor(acc[t], mask);
            acc[t] = acc[t] * s1 + ao * s2;
        }
        m = mn;
    }

    if (j == 0) {
        float inv = (deg > 0) ? (w / den) : 0.f;
        size_t base = (size_t)wid * 128 + h * 16;
        float o[16];
#pragma unroll
        for (int t = 0; t < 16; ++t) o[t] = acc[t] * inv;
        if (acc_in) {
#pragma unroll
            for (int t = 0; t < 16; ++t) o[t] += acc_in[base + t];
        }
        if (out_bf16) {
            unsigned short* op = (unsigned short*)outp + base;
            ushort4 p0, p1, p2, p3;
            p0.x = cvt_bf16(o[0]);  p0.y = cvt_bf16(o[1]);  p0.z = cvt_bf16(o[2]);  p0.w = cvt_bf16(o[3]);
            p1.x = cvt_bf16(o[4]);  p1.y = cvt_bf16(o[5]);  p1.z = cvt_bf16(o[6]);  p1.w = cvt_bf16(o[7]);
            p2.x = cvt_bf16(o[8]);  p2.y = cvt_bf16(o[9]);  p2.z = cvt_bf16(o[10]); p2.w = cvt_bf16(o[11]);
            p3.x = cvt_bf16(o[12]); p3.y = cvt_bf16(o[13]); p3.z = cvt_bf16(o[14]); p3.w = cvt_bf16(o[15]);
            ((ushort4*)op)[0] = p0; ((ushort4*)op)[1] = p1;
            ((ushort4*)op)[2] = p2; ((ushort4*)op)[3] = p3;
        } else {
            float* op = (float*)outp + base;
#pragma unroll
            for (int t = 0; t < 4; ++t)
                ((float4*)op)[t] = make_float4(o[4 * t], o[4 * t + 1], o[4 * t + 2], o[4 * t + 3]);
        }
    }
}

// ---------- launch ----------
extern "C" void kernel_launch(void* const* d_in, const int* in_sizes, int n_in,
                              void* d_out, int out_size, void* d_ws, size_t ws_size,
                              hipStream_t stream) {
    const float* h_a = (const float*)d_in[0];
    const float* h_b = (const float*)d_in[1];
    const int* srcs[3] = {(const int*)d_in[2], (const int*)d_in[4], (const int*)d_in[6]};
    const int* dsts[3] = {(const int*)d_in[3], (const int*)d_in[5], (const int*)d_in[7]};
    const float* Wk = (const float*)d_in[8];
    const float* bk = (const float*)d_in[9];
    const float* Wv = (const float*)d_in[10];
    const float* bv = (const float*)d_in[11];
    const float* Wq = (const float*)d_in[12];
    const float* bq = (const float*)d_in[13];
    const float* Wa = (const float*)d_in[14];
    const float* ba = (const float*)d_in[15];
    const float* att = (const float*)d_in[16];
    const float* msg = (const float*)d_in[17];
    const float* pri = (const float*)d_in[18];
    const float* skip = (const float*)d_in[19];

    const int N = in_sizes[0] / 128;
    const int E = in_sizes[2];
    const size_t NC = (size_t)N * 128;

    char* P = (char*)d_ws;
    auto alloc = [&](size_t bytes) { char* p = P; P += (bytes + 255) & ~(size_t)255; return p; };

    unsigned short* WkT = (unsigned short*)alloc(3 * 16384 * 2);
    unsigned short* WvT = (unsigned short*)alloc(3 * 16384 * 2);
    unsigned short* WqT = (unsigned short*)alloc(2 * 16384 * 2);
    unsigned short* WaT = (unsigned short*)alloc(2 * 16384 * 2);
    float* bkC = (float*)alloc(3 * 128 * 4);
    float* bvC = (float*)alloc(3 * 128 * 4);
    unsigned short* Xa16 = (unsigned short*)alloc(NC * 2);
    unsigned short* Xb16 = (unsigned short*)alloc(NC * 2);
    unsigned short* qa16 = (unsigned short*)alloc(NC * 2);
    unsigned short* qb16 = (unsigned short*)alloc(NC * 2);
    unsigned short* k16[3], *v16[3];
    for (int r = 0; r < 3; ++r) {
        k16[r] = (unsigned short*)alloc(NC * 2);
        v16[r] = (unsigned short*)alloc(NC * 2);
    }
    float* t_b = (float*)alloc(NC * 4);
    unsigned short* ta16 = (unsigned short*)alloc(NC * 2);
    unsigned short* tb16 = (unsigned short*)alloc(NC * 2);
    int *cnt[3], *offs[3], *fill[3], *ssb[3];
    for (int r = 0; r < 3; ++r) {
        cnt[r] = (int*)alloc((size_t)N * 4);
        offs[r] = (int*)alloc((size_t)N * 4);
        fill[r] = (int*)alloc((size_t)N * 4);
        ssb[r] = (int*)alloc((size_t)E * 4);
    }
    int* bsum = (int*)alloc(512 * 4);

    int eb = (E + 255) / 256;
    int scanb = (N + SCAN_B - 1) / SCAN_B;

    // CSR for all relations (independent of GEMMs)
    for (int r = 0; r < 3; ++r) {
        hipMemsetAsync(cnt[r], 0, (size_t)N * sizeof(int), stream);
        count_kernel<<<eb, 256, 0, stream>>>(dsts[r], cnt[r], E);
        scan1_kernel<<<scanb, SCAN_B, 0, stream>>>(cnt[r], offs[r], bsum, N);
        scan2_kernel<<<1, 512, 0, stream>>>(bsum, scanb);
        scan3_kernel<<<scanb, SCAN_B, 0, stream>>>(offs[r], bsum, fill[r], N);
        scatter_kernel<<<eb, 256, 0, stream>>>(srcs[r], dsts[r], fill[r], ssb[r], E);
    }

    // weight prep
    compose_kernel<<<(3 * 16384 + 255) / 256, 256, 0, stream>>>(
        Wk, bk, Wv, bv, att, msg, pri, WkT, WvT, bkC, bvC);
    tcast_kernel<<<64, 256, 0, stream>>>(Wq, WqT);
    tcast_kernel<<<64, 256, 0, stream>>>(Wq + 16384, WqT + 16384);
    tcast_kernel<<<64, 256, 0, stream>>>(Wa, WaT);
    tcast_kernel<<<64, 256, 0, stream>>>(Wa + 16384, WaT + 16384);

    // input casts
    int n4 = (int)(NC / 4);
    cast_kernel<<<(n4 + 255) / 256, 256, 0, stream>>>(h_a, Xa16, n4);
    cast_kernel<<<(n4 + 255) / 256, 256, 0, stream>>>(h_b, Xb16, n4);

    int gblocks = (N + 127) / 128;

    // projections: h_a -> q_a, k0, v0, k2, v2 ; h_b -> q_b, k1, v1
    OutSpecs sa;
    sa.o[0] = {WqT, bq, qa16};
    sa.o[1] = {WkT + 0 * 16384, bkC + 0 * 128, k16[0]};
    sa.o[2] = {WvT + 0 * 16384, bvC + 0 * 128, v16[0]};
    sa.o[3] = {WkT + 2 * 16384, bkC + 2 * 128, k16[2]};
    sa.o[4] = {WvT + 2 * 16384, bvC + 2 * 128, v16[2]};
    mfma_proj_kernel<<<gblocks, 256, 0, stream>>>(Xa16, N, sa, 5);

    OutSpecs sb;
    sb.o[0] = {WqT + 16384, bq + 128, qb16};
    sb.o[1] = {WkT + 1 * 16384, bkC + 1 * 128, k16[1]};
    sb.o[2] = {WvT + 1 * 16384, bvC + 1 * 128, v16[1]};
    sb.o[3] = {nullptr, nullptr, nullptr};
    sb.o[4] = {nullptr, nullptr, nullptr};
    mfma_proj_kernel<<<gblocks, 256, 0, stream>>>(Xb16, N, sb, 3);

    // aggregations (wave per node)
    int ab = (N + 3) / 4;   // 4 waves (nodes) per 256-thread block
    // r0: a->b, q=q_b, weight 0.5, write f32 partial t_b
    agg_kernel<<<ab, 256, 0, stream>>>(qb16, k16[0], v16[0], offs[0], cnt[0], ssb[0],
                                       nullptr, t_b, 0, 0.5f, N);
    // r1: b->a, q=q_a, weight 1.0, write bf16 t_a
    agg_kernel<<<ab, 256, 0, stream>>>(qa16, k16[1], v16[1], offs[1], cnt[1], ssb[1],
                                       nullptr, ta16, 1, 1.0f, N);
    // r2: a->b, q=q_b, weight 0.5, add t_b partial, write bf16 t_b
    agg_kernel<<<ab, 256, 0, stream>>>(qb16, k16[2], v16[2], offs[2], cnt[2], ssb[2],
                                       t_b, tb16, 1, 0.5f, N);

    // epilogue
    float* out = (float*)d_out;
    mfma_out_kernel<<<gblocks, 256, 0, stream>>>(ta16, N, WaT, ba, h_a, skip, 0, out);
    mfma_out_kernel<<<gblocks, 256, 0, stream>>>(tb16, N, WaT + 16384, ba + 128, h_b, skip, 1,
                                                 out + NC);
}